// Round 1
// baseline (1352.310 us; speedup 1.0000x reference)
//
#include <hip/hip_runtime.h>

#define L 1024
#define DD 1024
#define BATCH 32
#define M_TOTAL (BATCH * L)  // 32768

typedef _Float16 f16;
typedef __attribute__((ext_vector_type(4))) _Float16 f16x4;
typedef __attribute__((ext_vector_type(8))) _Float16 f16x8;
typedef __attribute__((ext_vector_type(4))) float f32x4;

// async global->LDS, 16B per lane. LDS dest = wave-uniform base + lane*16.
__device__ __forceinline__ void load16_lds(const void* g, void* l) {
  __builtin_amdgcn_global_load_lds(
      (const __attribute__((address_space(1))) unsigned int*)g,
      (__attribute__((address_space(3))) unsigned int*)l,
      16, 0, 0);
}

// ---------------- small prep kernels ----------------

// x[b,l,:] = (f16)(item_emb[positives[b,l],:] + pos_emb[l,:])
__global__ void gather_x_kernel(const int* __restrict__ positives,
                                const float* __restrict__ item_emb,
                                const float* __restrict__ pos_emb,
                                f16* __restrict__ x) {
  const int bl = blockIdx.x;
  const int lpos = bl & (L - 1);
  const int idx = positives[bl];
  const int d = threadIdx.x * 4;
  const float4 ie = *(const float4*)(item_emb + (size_t)idx * DD + d);
  const float4 pe = *(const float4*)(pos_emb + (size_t)lpos * DD + d);
  f16x4 h;
  h[0] = (f16)(ie.x + pe.x);
  h[1] = (f16)(ie.y + pe.y);
  h[2] = (f16)(ie.z + pe.z);
  h[3] = (f16)(ie.w + pe.w);
  *(f16x4*)(x + (size_t)bl * DD + d) = h;
}

// f32 -> f16 cast of a 1024x1024 weight matrix (1M elems, grid 1024x256x4)
__global__ void cast_w_kernel(const float* __restrict__ src, f16* __restrict__ dst) {
  const int i = (blockIdx.x * 256 + threadIdx.x) * 4;
  const float4 v = *(const float4*)(src + i);
  f16x4 h;
  h[0] = (f16)v.x; h[1] = (f16)v.y; h[2] = (f16)v.z; h[3] = (f16)v.w;
  *(f16x4*)(dst + i) = h;
}

// per-batch 1024x1024 f16 transpose via 64x64 LDS tiles
__global__ void transpose_v_kernel(const unsigned short* __restrict__ vin,
                                   unsigned short* __restrict__ vout) {
  const int b = blockIdx.z;
  const unsigned short* in = vin + (size_t)b * L * DD;
  unsigned short* out = vout + (size_t)b * L * DD;
  const int r0 = blockIdx.x * 64, c0 = blockIdx.y * 64;
  __shared__ unsigned short t[64][65];
  const int tid = threadIdx.x;
  for (int c = tid; c < 1024; c += 256) {
    const int r = c >> 4, cc = (c & 15) * 4;
    const ushort4 vv = *(const ushort4*)(in + (size_t)(r0 + r) * DD + c0 + cc);
    t[r][cc] = vv.x; t[r][cc + 1] = vv.y; t[r][cc + 2] = vv.z; t[r][cc + 3] = vv.w;
  }
  __syncthreads();
  for (int c = tid; c < 1024; c += 256) {
    const int r = c >> 4, cc = (c & 15) * 4;
    ushort4 vv;
    vv.x = t[cc][r]; vv.y = t[cc + 1][r]; vv.z = t[cc + 2][r]; vv.w = t[cc + 3][r];
    *(ushort4*)(out + (size_t)(c0 + r) * L + r0 + cc) = vv;
  }
}

// ---------------- GEMM: C = A(MxK) * B^T (B is NxK row-major), f16 in, f32 acc ---------
// 128x128 tile, BK=32, 256 threads = 4 waves (2x2), each wave 4x4 MFMAs of 16x16x32.
// LDS layout [kquad][m][8] halves: ds_read_b128 hits all 32 banks evenly.
// EPI 0: silu -> f16.  EPI 1: (acc*gamma[col]+beta[col])*scale -> f16.

template <int EPI>
__global__ __launch_bounds__(256) void gemm_bt_kernel(
    const f16* __restrict__ A, const f16* __restrict__ B, f16* __restrict__ Cout,
    const int M, const int N, const int K,
    const float* __restrict__ gamma, const float* __restrict__ beta, const float scale) {
  __shared__ f16 As[4][128][8];
  __shared__ f16 Bs[4][128][8];
  const int tm0 = blockIdx.x * 128;
  const int tn0 = blockIdx.y * 128;
  const int tid = threadIdx.x;
  const int w = tid >> 6, l = tid & 63;
  const int wr = w >> 1, wc = w & 1;
  const int qd = l >> 4, mlo = l & 15;
  f32x4 acc[4][4] = {};
  for (int k0 = 0; k0 < K; k0 += 32) {
#pragma unroll
    for (int s = 0; s < 2; ++s) {
      const int t = w * 2 + s;
      const int q = t >> 1, mh = t & 1;
      load16_lds(A + (size_t)(tm0 + mh * 64 + l) * K + k0 + q * 8, &As[q][mh * 64][0]);
      load16_lds(B + (size_t)(tn0 + mh * 64 + l) * K + k0 + q * 8, &Bs[q][mh * 64][0]);
    }
    __syncthreads();
    f16x8 af[4], bf[4];
#pragma unroll
    for (int i = 0; i < 4; ++i) af[i] = *(const f16x8*)&As[qd][wr * 64 + i * 16 + mlo][0];
#pragma unroll
    for (int j = 0; j < 4; ++j) bf[j] = *(const f16x8*)&Bs[qd][wc * 64 + j * 16 + mlo][0];
#pragma unroll
    for (int i = 0; i < 4; ++i)
#pragma unroll
      for (int j = 0; j < 4; ++j)
        acc[i][j] = __builtin_amdgcn_mfma_f32_16x16x32_f16(af[i], bf[j], acc[i][j], 0, 0, 0);
    __syncthreads();
  }
#pragma unroll
  for (int i = 0; i < 4; ++i) {
#pragma unroll
    for (int j = 0; j < 4; ++j) {
#pragma unroll
      for (int r = 0; r < 4; ++r) {
        const int gm = tm0 + wr * 64 + i * 16 + (l >> 4) * 4 + r;
        const int gn = tn0 + wc * 64 + j * 16 + (l & 15);
        float y = acc[i][j][r];
        if (EPI == 0) {
          y = y / (1.0f + __expf(-y));  // silu
        } else {
          y = (y * gamma[gn] + beta[gn]) * scale;
        }
        Cout[(size_t)gm * N + gn] = (f16)y;
      }
    }
  }
}

// ---------------- QK^T (causal, masked, relu^2) -> P~ (f16) ----------------
// q,k pre-scaled by 2^11 each => acc = S * 2^22.  P~ = relu(acc*sparse_w)^2 (masked).
__global__ __launch_bounds__(256) void qk_kernel(
    const f16* __restrict__ Q, const f16* __restrict__ Km,
    const int* __restrict__ mask, const float* __restrict__ sparse_w,
    f16* __restrict__ P) {
  const int qt = blockIdx.x, kt = blockIdx.y, b = blockIdx.z;
  if (kt > qt) return;
  const f16* A = Q + (size_t)b * L * L;
  const f16* B = Km + (size_t)b * L * L;
  const int* mb = mask + b * L;
  f16* Pb = P + (size_t)b * L * L;
  __shared__ f16 As[4][128][8];
  __shared__ f16 Bs[4][128][8];
  const int tm0 = qt * 128, tn0 = kt * 128;
  const int tid = threadIdx.x;
  const int w = tid >> 6, l = tid & 63;
  const int wr = w >> 1, wc = w & 1;
  const int qd = l >> 4, mlo = l & 15;
  f32x4 acc[4][4] = {};
  for (int k0 = 0; k0 < L; k0 += 32) {
#pragma unroll
    for (int s = 0; s < 2; ++s) {
      const int t = w * 2 + s;
      const int q = t >> 1, mh = t & 1;
      load16_lds(A + (size_t)(tm0 + mh * 64 + l) * L + k0 + q * 8, &As[q][mh * 64][0]);
      load16_lds(B + (size_t)(tn0 + mh * 64 + l) * L + k0 + q * 8, &Bs[q][mh * 64][0]);
    }
    __syncthreads();
    f16x8 af[4], bf[4];
#pragma unroll
    for (int i = 0; i < 4; ++i) af[i] = *(const f16x8*)&As[qd][wr * 64 + i * 16 + mlo][0];
#pragma unroll
    for (int j = 0; j < 4; ++j) bf[j] = *(const f16x8*)&Bs[qd][wc * 64 + j * 16 + mlo][0];
#pragma unroll
    for (int i = 0; i < 4; ++i)
#pragma unroll
      for (int j = 0; j < 4; ++j)
        acc[i][j] = __builtin_amdgcn_mfma_f32_16x16x32_f16(af[i], bf[j], acc[i][j], 0, 0, 0);
    __syncthreads();
  }
#pragma unroll
  for (int i = 0; i < 4; ++i) {
#pragma unroll
    for (int j = 0; j < 4; ++j) {
#pragma unroll
      for (int r = 0; r < 4; ++r) {
        const int gq = tm0 + wr * 64 + i * 16 + (l >> 4) * 4 + r;
        const int gk = tn0 + wc * 64 + j * 16 + (l & 15);
        float p = 0.0f;
        const bool blocked = (gk > gq) || ((gk != gq) && (mb[gk] == 0));
        if (!blocked) {
          p = acc[i][j][r] * sparse_w[(size_t)gq * L + gk];
          p = fmaxf(p, 0.0f);
          p = p * p;
        }
        Pb[(size_t)gq * L + gk] = (f16)p;
      }
    }
  }
}

// ---------------- PV: out = (P~ @ V) * 2^-64 (causal K-bound), f32 out ----------------
__global__ __launch_bounds__(256) void pv_kernel(
    const f16* __restrict__ P, const f16* __restrict__ Vt, float* __restrict__ Out) {
  const int qt = blockIdx.x, nt = blockIdx.y, b = blockIdx.z;
  const f16* A = P + (size_t)b * L * L;
  const f16* B = Vt + (size_t)b * L * DD;  // Vt is [d][ki] per batch
  float* outb = Out + (size_t)b * L * DD;
  const int kmax = (qt + 1) * 128;
  __shared__ f16 As[4][128][8];
  __shared__ f16 Bs[4][128][8];
  const int tm0 = qt * 128, tn0 = nt * 128;
  const int tid = threadIdx.x;
  const int w = tid >> 6, l = tid & 63;
  const int wr = w >> 1, wc = w & 1;
  const int qd = l >> 4, mlo = l & 15;
  f32x4 acc[4][4] = {};
  for (int k0 = 0; k0 < kmax; k0 += 32) {
#pragma unroll
    for (int s = 0; s < 2; ++s) {
      const int t = w * 2 + s;
      const int q = t >> 1, mh = t & 1;
      load16_lds(A + (size_t)(tm0 + mh * 64 + l) * L + k0 + q * 8, &As[q][mh * 64][0]);
      load16_lds(B + (size_t)(tn0 + mh * 64 + l) * L + k0 + q * 8, &Bs[q][mh * 64][0]);
    }
    __syncthreads();
    f16x8 af[4], bf[4];
#pragma unroll
    for (int i = 0; i < 4; ++i) af[i] = *(const f16x8*)&As[qd][wr * 64 + i * 16 + mlo][0];
#pragma unroll
    for (int j = 0; j < 4; ++j) bf[j] = *(const f16x8*)&Bs[qd][wc * 64 + j * 16 + mlo][0];
#pragma unroll
    for (int i = 0; i < 4; ++i)
#pragma unroll
      for (int j = 0; j < 4; ++j)
        acc[i][j] = __builtin_amdgcn_mfma_f32_16x16x32_f16(af[i], bf[j], acc[i][j], 0, 0, 0);
    __syncthreads();
  }
  // true out = acc * 2^-44 (q,k scales) * 2^-20 (1/(L*D)) = acc * 2^-64
  const float fin = 5.421010862427522e-20f;  // 2^-64
#pragma unroll
  for (int i = 0; i < 4; ++i) {
#pragma unroll
    for (int j = 0; j < 4; ++j) {
#pragma unroll
      for (int r = 0; r < 4; ++r) {
        const int gq = tm0 + wr * 64 + i * 16 + (l >> 4) * 4 + r;
        const int gd = tn0 + wc * 64 + j * 16 + (l & 15);
        outb[(size_t)gq * DD + gd] = acc[i][j][r] * fin;
      }
    }
  }
}

// ---------------- launch ----------------
extern "C" void kernel_launch(void* const* d_in, const int* in_sizes, int n_in,
                              void* d_out, int out_size, void* d_ws, size_t ws_size,
                              hipStream_t stream) {
  const int* positives = (const int*)d_in[0];
  const int* mask = (const int*)d_in[1];
  const float* item_emb = (const float*)d_in[2];
  const float* pos_emb = (const float*)d_in[3];
  const float* Wz = (const float*)d_in[4];
  const float* Wv = (const float*)d_in[5];
  const float* Wq = (const float*)d_in[6];
  const float* Wk = (const float*)d_in[7];
  const float* gamma_q = (const float*)d_in[8];   // (2,L) -> head 0 = first L
  const float* beta_q = (const float*)d_in[9];
  const float* gamma_k = (const float*)d_in[10];
  const float* beta_k = (const float*)d_in[11];
  const float* sparse_w = (const float*)d_in[12];
  float* out = (float*)d_out;

  char* ws = (char*)d_ws;
  const size_t MB = 1024 * 1024;
  f16* Wzh = (f16*)(ws + 0 * MB);
  f16* Wvh = (f16*)(ws + 2 * MB);
  f16* Wqh = (f16*)(ws + 4 * MB);
  f16* Wkh = (f16*)(ws + 6 * MB);
  // four 64MB f16 buffers with reuse (peak ws = 264MB):
  f16* bufA = (f16*)(ws + 8 * MB);    // x, then q
  f16* bufB = (f16*)(ws + 72 * MB);   // z, then vT
  f16* bufC = (f16*)(ws + 136 * MB);  // v, then P~
  f16* bufD = (f16*)(ws + 200 * MB);  // k

  cast_w_kernel<<<1024, 256, 0, stream>>>(Wz, Wzh);
  cast_w_kernel<<<1024, 256, 0, stream>>>(Wv, Wvh);
  cast_w_kernel<<<1024, 256, 0, stream>>>(Wq, Wqh);
  cast_w_kernel<<<1024, 256, 0, stream>>>(Wk, Wkh);
  gather_x_kernel<<<M_TOTAL, 256, 0, stream>>>(positives, item_emb, pos_emb, bufA);

  const dim3 g1(M_TOTAL / 128, L / 128);  // 256 x 8
  // z = silu(x Wz^T)
  gemm_bt_kernel<0><<<g1, 256, 0, stream>>>(bufA, Wzh, bufB, M_TOTAL, L, DD, nullptr, nullptr, 1.0f);
  // v = silu(x Wv^T)
  gemm_bt_kernel<0><<<g1, 256, 0, stream>>>(bufA, Wvh, bufC, M_TOTAL, DD, DD, nullptr, nullptr, 1.0f);
  // q~ = (z Wq^T * gamma_q + beta_q) * 2^11   (overwrites x in bufA)
  gemm_bt_kernel<1><<<g1, 256, 0, stream>>>(bufB, Wqh, bufA, M_TOTAL, L, L, gamma_q, beta_q, 2048.0f);
  // k~ = (z Wk^T * gamma_k + beta_k) * 2^11
  gemm_bt_kernel<1><<<g1, 256, 0, stream>>>(bufB, Wkh, bufD, M_TOTAL, L, L, gamma_k, beta_k, 2048.0f);

  // vT (overwrites z in bufB)
  const dim3 gt(16, 16, BATCH);
  transpose_v_kernel<<<gt, 256, 0, stream>>>((const unsigned short*)bufC, (unsigned short*)bufB);

  // P~ = relu(S~ * sparse_w)^2 masked, lower-tri tiles only (overwrites v in bufC)
  const dim3 gqk(8, 8, BATCH);
  qk_kernel<<<gqk, 256, 0, stream>>>(bufA, bufD, mask, sparse_w, bufC);

  // out = (P~ @ V) * 2^-64
  pv_kernel<<<gqk, 256, 0, stream>>>(bufC, bufB, out);
}

// Round 2
// 1268.540 us; speedup vs baseline: 1.0660x; 1.0660x over previous
//
#include <hip/hip_runtime.h>

#define L 1024
#define DD 1024
#define BATCH 32
#define M_TOTAL (BATCH * L)  // 32768

typedef _Float16 f16;
typedef __attribute__((ext_vector_type(4))) _Float16 f16x4;
typedef __attribute__((ext_vector_type(8))) _Float16 f16x8;
typedef __attribute__((ext_vector_type(4))) float f32x4;

// async global->LDS, 16B per lane. LDS dest = wave-uniform base + lane*16.
__device__ __forceinline__ void load16_lds(const void* g, void* l) {
  __builtin_amdgcn_global_load_lds(
      (const __attribute__((address_space(1))) unsigned int*)g,
      (__attribute__((address_space(3))) unsigned int*)l,
      16, 0, 0);
}

// ---------------- small prep kernels ----------------

__global__ void gather_x_kernel(const int* __restrict__ positives,
                                const float* __restrict__ item_emb,
                                const float* __restrict__ pos_emb,
                                f16* __restrict__ x) {
  const int bl = blockIdx.x;
  const int lpos = bl & (L - 1);
  const int idx = positives[bl];
  const int d = threadIdx.x * 4;
  const float4 ie = *(const float4*)(item_emb + (size_t)idx * DD + d);
  const float4 pe = *(const float4*)(pos_emb + (size_t)lpos * DD + d);
  f16x4 h;
  h[0] = (f16)(ie.x + pe.x);
  h[1] = (f16)(ie.y + pe.y);
  h[2] = (f16)(ie.z + pe.z);
  h[3] = (f16)(ie.w + pe.w);
  *(f16x4*)(x + (size_t)bl * DD + d) = h;
}

__global__ void cast_w_kernel(const float* __restrict__ src, f16* __restrict__ dst) {
  const int i = (blockIdx.x * 256 + threadIdx.x) * 4;
  const float4 v = *(const float4*)(src + i);
  f16x4 h;
  h[0] = (f16)v.x; h[1] = (f16)v.y; h[2] = (f16)v.z; h[3] = (f16)v.w;
  *(f16x4*)(dst + i) = h;
}

// per-batch 1024x1024 f16 transpose via 64x64 LDS tiles
__global__ void transpose_v_kernel(const unsigned short* __restrict__ vin,
                                   unsigned short* __restrict__ vout) {
  const int b = blockIdx.z;
  const unsigned short* in = vin + (size_t)b * L * DD;
  unsigned short* out = vout + (size_t)b * L * DD;
  const int r0 = blockIdx.x * 64, c0 = blockIdx.y * 64;
  __shared__ unsigned short t[64][65];
  const int tid = threadIdx.x;
  for (int c = tid; c < 1024; c += 256) {
    const int r = c >> 4, cc = (c & 15) * 4;
    const ushort4 vv = *(const ushort4*)(in + (size_t)(r0 + r) * DD + c0 + cc);
    t[r][cc] = vv.x; t[r][cc + 1] = vv.y; t[r][cc + 2] = vv.z; t[r][cc + 3] = vv.w;
  }
  __syncthreads();
  for (int c = tid; c < 1024; c += 256) {
    const int r = c >> 4, cc = (c & 15) * 4;
    ushort4 vv;
    vv.x = t[cc][r]; vv.y = t[cc + 1][r]; vv.z = t[cc + 2][r]; vv.w = t[cc + 3][r];
    *(ushort4*)(out + (size_t)(c0 + r) * L + r0 + cc) = vv;
  }
}

// ---------------- dense GEMM: C = A(MxK,ldA) * B^T (NxK row-major), f16->f32 acc ------
// 128x128 tile, BK=32, 4 waves. 1-D grid with 16-mtile supertile swizzle for L2 reuse.
// EPI 0: silu. EPI 1: (acc*gamma+beta)*scale with gn>=1024 -> (g1,b1).
template <int EPI, int NT>  // NT = N/128, power of 2
__global__ __launch_bounds__(256) void gemm_bt_kernel(
    const f16* __restrict__ A, const f16* __restrict__ B, f16* __restrict__ Cout,
    const size_t ldA, const size_t ldC,
    const float* __restrict__ g0, const float* __restrict__ b0,
    const float* __restrict__ g1, const float* __restrict__ b1, const float scale) {
  __shared__ f16 As[4][128][8];
  __shared__ f16 Bs[4][128][8];
  // swizzle: consecutive blocks cover 16 m-tiles x all NT n-tiles
  const int bid = blockIdx.x;
  const int per = NT * 16;
  const int st = bid / per, wi = bid % per;
  const int mt = st * 16 + (wi & 15);
  const int nt = wi >> 4;
  const int tm0 = mt * 128, tn0 = nt * 128;
  const int N = NT * 128;
  const int tid = threadIdx.x;
  const int w = tid >> 6, l = tid & 63;
  const int wr = w >> 1, wc = w & 1;
  const int qd = l >> 4, mlo = l & 15;
  f32x4 acc[4][4] = {};
  for (int k0 = 0; k0 < 1024; k0 += 32) {
#pragma unroll
    for (int s = 0; s < 2; ++s) {
      const int t = w * 2 + s;
      const int q = t >> 1, mh = t & 1;
      load16_lds(A + (size_t)(tm0 + mh * 64 + l) * ldA + k0 + q * 8, &As[q][mh * 64][0]);
      load16_lds(B + (size_t)(tn0 + mh * 64 + l) * 1024 + k0 + q * 8, &Bs[q][mh * 64][0]);
    }
    __syncthreads();
    f16x8 af[4], bf[4];
#pragma unroll
    for (int i = 0; i < 4; ++i) af[i] = *(const f16x8*)&As[qd][wr * 64 + i * 16 + mlo][0];
#pragma unroll
    for (int j = 0; j < 4; ++j) bf[j] = *(const f16x8*)&Bs[qd][wc * 64 + j * 16 + mlo][0];
#pragma unroll
    for (int i = 0; i < 4; ++i)
#pragma unroll
      for (int j = 0; j < 4; ++j)
        acc[i][j] = __builtin_amdgcn_mfma_f32_16x16x32_f16(af[i], bf[j], acc[i][j], 0, 0, 0);
    __syncthreads();
  }
#pragma unroll
  for (int i = 0; i < 4; ++i) {
#pragma unroll
    for (int j = 0; j < 4; ++j) {
      const int gn = tn0 + wc * 64 + j * 16 + mlo;
      float gg = 1.0f, bb = 0.0f;
      if (EPI == 1) {
        gg = (gn < 1024) ? g0[gn] : g1[gn - 1024];
        bb = (gn < 1024) ? b0[gn] : b1[gn - 1024];
      }
#pragma unroll
      for (int r = 0; r < 4; ++r) {
        const int gm = tm0 + wr * 64 + i * 16 + qd * 4 + r;
        float y = acc[i][j][r];
        if (EPI == 0) {
          y = y / (1.0f + __expf(-y));  // silu
        } else {
          y = (y * gg + bb) * scale;
        }
        Cout[(size_t)gm * ldC + gn] = (f16)y;
      }
    }
  }
}

// ---------------- QK^T (causal, masked, relu^2) -> P~ (f16) ----------------
// 64x128 tiles: active iff 2*kt <= qt -> 72 tiles/batch, 2304 blocks total.
// q,k pre-scaled by 2^11 each => acc = S * 2^22.  P~ = relu(acc*sparse_w)^2 (masked).
__global__ __launch_bounds__(256) void qk_kernel(
    const f16* __restrict__ QK,  // (32768 x 2048): cols [0,1024)=q~, [1024,2048)=k~
    const int* __restrict__ mask, const float* __restrict__ sparse_w,
    f16* __restrict__ P) {
  const int qt = blockIdx.x, kt = blockIdx.y, b = blockIdx.z;
  if (kt * 2 > qt) return;
  const f16* A = QK + (size_t)b * L * 2048;          // q~ rows of this batch
  const f16* B = QK + (size_t)b * L * 2048 + 1024;   // k~ rows
  const int* mb = mask + b * L;
  f16* Pb = P + (size_t)b * L * L;
  __shared__ f16 As[4][64][8];    // 4KB
  __shared__ f16 Bs[4][128][8];   // 8KB
  const int tm0 = qt * 64, tn0 = kt * 128;
  const int tid = threadIdx.x;
  const int w = tid >> 6, l = tid & 63;
  const int wr = w >> 1, wc = w & 1;   // wave covers 32 rows x 64 cols
  const int qd = l >> 4, mlo = l & 15;
  f32x4 acc[2][4] = {};
  for (int k0 = 0; k0 < L; k0 += 32) {
    // A: 64 rows x 32k = 4KB = one block-wide load; wave w stages k-chunk q=w
    load16_lds(A + (size_t)(tm0 + l) * 2048 + k0 + w * 8, &As[w][0][0]);
#pragma unroll
    for (int s = 0; s < 2; ++s)
      load16_lds(B + (size_t)(tn0 + s * 64 + l) * 2048 + k0 + w * 8, &Bs[w][s * 64][0]);
    __syncthreads();
    f16x8 af[2], bf[4];
#pragma unroll
    for (int i = 0; i < 2; ++i) af[i] = *(const f16x8*)&As[qd][wr * 32 + i * 16 + mlo][0];
#pragma unroll
    for (int j = 0; j < 4; ++j) bf[j] = *(const f16x8*)&Bs[qd][wc * 64 + j * 16 + mlo][0];
#pragma unroll
    for (int i = 0; i < 2; ++i)
#pragma unroll
      for (int j = 0; j < 4; ++j)
        acc[i][j] = __builtin_amdgcn_mfma_f32_16x16x32_f16(af[i], bf[j], acc[i][j], 0, 0, 0);
    __syncthreads();
  }
#pragma unroll
  for (int i = 0; i < 2; ++i) {
#pragma unroll
    for (int j = 0; j < 4; ++j) {
      const int gk = tn0 + wc * 64 + j * 16 + mlo;
      const int mk = mb[gk];
#pragma unroll
      for (int r = 0; r < 4; ++r) {
        const int gq = tm0 + wr * 32 + i * 16 + qd * 4 + r;
        float p = 0.0f;
        const bool blocked = (gk > gq) || ((gk != gq) && (mk == 0));
        if (!blocked) {
          p = acc[i][j][r] * sparse_w[(size_t)gq * L + gk];
          p = fmaxf(p, 0.0f);
          p = p * p;
        }
        Pb[(size_t)gq * L + gk] = (f16)p;
      }
    }
  }
}

// ---------------- PV: out = (P~ @ V) * 2^-64 (causal K-bound), f32 out ----------------
__global__ __launch_bounds__(256) void pv_kernel(
    const f16* __restrict__ P, const f16* __restrict__ Vt, float* __restrict__ Out) {
  const int qt = blockIdx.x, nt = blockIdx.y, b = blockIdx.z;
  const f16* A = P + (size_t)b * L * L;
  const f16* B = Vt + (size_t)b * L * DD;  // Vt is [d][ki] per batch
  float* outb = Out + (size_t)b * L * DD;
  const int kmax = (qt + 1) * 128;
  __shared__ f16 As[4][128][8];
  __shared__ f16 Bs[4][128][8];
  const int tm0 = qt * 128, tn0 = nt * 128;
  const int tid = threadIdx.x;
  const int w = tid >> 6, l = tid & 63;
  const int wr = w >> 1, wc = w & 1;
  const int qd = l >> 4, mlo = l & 15;
  f32x4 acc[4][4] = {};
  for (int k0 = 0; k0 < kmax; k0 += 32) {
#pragma unroll
    for (int s = 0; s < 2; ++s) {
      const int t = w * 2 + s;
      const int q = t >> 1, mh = t & 1;
      load16_lds(A + (size_t)(tm0 + mh * 64 + l) * L + k0 + q * 8, &As[q][mh * 64][0]);
      load16_lds(B + (size_t)(tn0 + mh * 64 + l) * L + k0 + q * 8, &Bs[q][mh * 64][0]);
    }
    __syncthreads();
    f16x8 af[4], bf[4];
#pragma unroll
    for (int i = 0; i < 4; ++i) af[i] = *(const f16x8*)&As[qd][wr * 64 + i * 16 + mlo][0];
#pragma unroll
    for (int j = 0; j < 4; ++j) bf[j] = *(const f16x8*)&Bs[qd][wc * 64 + j * 16 + mlo][0];
#pragma unroll
    for (int i = 0; i < 4; ++i)
#pragma unroll
      for (int j = 0; j < 4; ++j)
        acc[i][j] = __builtin_amdgcn_mfma_f32_16x16x32_f16(af[i], bf[j], acc[i][j], 0, 0, 0);
    __syncthreads();
  }
  const float fin = 5.421010862427522e-20f;  // 2^-64 = 2^-44 (qk scales) * 2^-20 (1/(L*D))
#pragma unroll
  for (int i = 0; i < 4; ++i) {
#pragma unroll
    for (int j = 0; j < 4; ++j) {
#pragma unroll
      for (int r = 0; r < 4; ++r) {
        const int gq = tm0 + wr * 64 + i * 16 + qd * 4 + r;
        const int gd = tn0 + wc * 64 + j * 16 + mlo;
        outb[(size_t)gq * DD + gd] = acc[i][j][r] * fin;
      }
    }
  }
}

// ---------------- launch ----------------
extern "C" void kernel_launch(void* const* d_in, const int* in_sizes, int n_in,
                              void* d_out, int out_size, void* d_ws, size_t ws_size,
                              hipStream_t stream) {
  const int* positives = (const int*)d_in[0];
  const int* mask = (const int*)d_in[1];
  const float* item_emb = (const float*)d_in[2];
  const float* pos_emb = (const float*)d_in[3];
  const float* Wz = (const float*)d_in[4];
  const float* Wv = (const float*)d_in[5];
  const float* Wq = (const float*)d_in[6];
  const float* Wk = (const float*)d_in[7];
  const float* gamma_q = (const float*)d_in[8];   // (2,L) -> head 0 = first L
  const float* beta_q = (const float*)d_in[9];
  const float* gamma_k = (const float*)d_in[10];
  const float* beta_k = (const float*)d_in[11];
  const float* sparse_w = (const float*)d_in[12];
  float* out = (float*)d_out;

  char* ws = (char*)d_ws;
  const size_t MB = 1024 * 1024;
  // layout (peak 264MB, known-good):
  //  [0,2)   Wzh      [2,4)  Wvh      [4,8)  Wqkh (stacked 2048x1024)
  //  [8,72)  bufZ: z, later vT
  //  [72,136) bufV: v, later P~
  //  [136,264) bufQK: x (first 64MB, dead after v-gemm), then q~|k~ (128MB)
  f16* Wzh = (f16*)(ws + 0 * MB);
  f16* Wvh = (f16*)(ws + 2 * MB);
  f16* Wqkh = (f16*)(ws + 4 * MB);
  f16* bufZ = (f16*)(ws + 8 * MB);
  f16* bufV = (f16*)(ws + 72 * MB);
  f16* bufQK = (f16*)(ws + 136 * MB);
  f16* bufX = bufQK;  // x occupies first 64MB of QK region until overwritten

  cast_w_kernel<<<1024, 256, 0, stream>>>(Wz, Wzh);
  cast_w_kernel<<<1024, 256, 0, stream>>>(Wv, Wvh);
  cast_w_kernel<<<1024, 256, 0, stream>>>(Wq, Wqkh);             // rows [0,1024)
  cast_w_kernel<<<1024, 256, 0, stream>>>(Wk, Wqkh + 1024 * 1024);  // rows [1024,2048)
  gather_x_kernel<<<M_TOTAL, 256, 0, stream>>>(positives, item_emb, pos_emb, bufX);

  // z = silu(x Wz^T), v = silu(x Wv^T): grid 2048, supertile-swizzled
  gemm_bt_kernel<0, 8><<<2048, 256, 0, stream>>>(bufX, Wzh, bufZ, 1024, 1024,
                                                 nullptr, nullptr, nullptr, nullptr, 1.0f);
  gemm_bt_kernel<0, 8><<<2048, 256, 0, stream>>>(bufX, Wvh, bufV, 1024, 1024,
                                                 nullptr, nullptr, nullptr, nullptr, 1.0f);
  // [q~|k~] = (z [Wq;Wk]^T * gamma + beta) * 2^11 -> bufQK (overwrites dead x)
  gemm_bt_kernel<1, 16><<<4096, 256, 0, stream>>>(bufZ, Wqkh, bufQK, 1024, 2048,
                                                  gamma_q, beta_q, gamma_k, beta_k, 2048.0f);
  // vT (overwrites z in bufZ — safe: qk-proj already consumed z, stream-ordered)
  const dim3 gt(16, 16, BATCH);
  transpose_v_kernel<<<gt, 256, 0, stream>>>((const unsigned short*)bufV, (unsigned short*)bufZ);
  // P~ = relu(S~ * sparse_w)^2 masked (overwrites v in bufV)
  const dim3 gqk(16, 8, BATCH);
  qk_kernel<<<gqk, 256, 0, stream>>>(bufQK, mask, sparse_w, bufV);
  // out = (P~ @ V) * 2^-64
  const dim3 gpv(8, 8, BATCH);
  pv_kernel<<<gpv, 256, 0, stream>>>(bufV, bufZ, out);
}